// Round 10
// baseline (6879.330 us; speedup 1.0000x reference)
//
#include <hip/hip_runtime.h>
#include <hip/hip_bf16.h>
#include <math.h>

#define B_ 8
#define S_ 4096
#define D_ 768
#define NH_ 4
#define DH_ 192
#define NTOT_ 768   // 4*DH_

typedef __attribute__((ext_vector_type(8))) short short8;
typedef __attribute__((ext_vector_type(4))) float floatx4;
typedef __attribute__((ext_vector_type(4))) short short4v;
typedef __attribute__((ext_vector_type(4))) unsigned int uint4v;
typedef _Float16 f16;

__device__ __forceinline__ short f2bs(float f) {
  union { float f; unsigned u; } v; v.f = f;
  unsigned r = v.u + 0x7FFFu + ((v.u >> 16) & 1u);
  return (short)(r >> 16);
}
__device__ __forceinline__ float bs2f(unsigned short s) {
  union { unsigned u; float f; } v; v.u = ((unsigned)s) << 16;
  return v.f;
}
__device__ __forceinline__ unsigned packh2(float lo, float hi) {
  union { f16 h[2]; unsigned u; } x;
  x.h[0] = (f16)lo; x.h[1] = (f16)hi;
  return x.u;
}

// Full-rate f32-pipe replacement for v_dot2_f32_f16 (which measures as
// quarter-rate across R3-R9): two v_fma_mix_f32, f16 inputs via op_sel,
// f32 accumulate. acc += lo(r)*lo(y) ; acc += hi(r)*hi(y).
__device__ __forceinline__ float FMAMIX2(unsigned r, unsigned y, float acc) {
  asm("v_fma_mix_f32 %0, %1, %2, %0 op_sel_hi:[1,1,0]\n\t"
      "v_fma_mix_f32 %0, %1, %2, %0 op_sel:[1,1,0] op_sel_hi:[1,1,0]"
      : "+v"(acc) : "v"(r), "v"(y));
  return acc;
}

// quad-perm DPP (register-only cross-lane within quad)
template<int CTRL>
__device__ __forceinline__ float qperm(float x) {
  return __int_as_float(__builtin_amdgcn_mov_dpp(__float_as_int(x), CTRL, 0xf, 0xf, true));
}

// ---------------- K0: weights -> bf16, fragment-friendly [hg][o][d] ----------------
__global__ __launch_bounds__(256) void wconv_kernel(
    const float* __restrict__ wf, const float* __restrict__ wi,
    const float* __restrict__ wz, const float* __restrict__ wo,
    short* __restrict__ Wbf)
{
  int idx = blockIdx.x * 256 + threadIdx.x;      // < 16*36864
  int hg = idx / (DH_ * DH_);
  int r  = idx % (DH_ * DH_);
  int h = hg >> 2, g = hg & 3;
  const float* W = (g == 0) ? wf : (g == 1) ? wi : (g == 2) ? wz : wo;
  Wbf[idx] = f2bs(W[(size_t)h * DH_ * DH_ + r]);
}

// ---------------- K1: depthwise causal conv + SiLU; also bf16 copy of x ----------------
__global__ __launch_bounds__(256) void conv_silu_kernel(
    const float* __restrict__ x, const float* __restrict__ cw, const float* __restrict__ cb,
    short* __restrict__ xb, short* __restrict__ xcb)
{
  const int b  = blockIdx.x / (S_ / 64);
  const int s0 = (blockIdx.x % (S_ / 64)) * 64;
  const int tid = threadIdx.x;
  float wv[3][4], bias[3], win[3][3];
  for (int j = 0; j < 3; ++j) {
    int d = tid + j * 256;
    for (int k = 0; k < 4; ++k) wv[j][k] = cw[d * 4 + k];
    bias[j] = cb[d];
    for (int p = 0; p < 3; ++p) {
      int s = s0 - 3 + p;
      win[j][p] = (s >= 0) ? x[((size_t)b * S_ + s) * D_ + d] : 0.f;
    }
  }
  for (int i = 0; i < 64; ++i) {
    size_t base = ((size_t)b * S_ + (s0 + i)) * D_;
    for (int j = 0; j < 3; ++j) {
      int d = tid + j * 256;
      float xc = x[base + d];
      float a = bias[j] + win[j][0] * wv[j][0] + win[j][1] * wv[j][1]
                        + win[j][2] * wv[j][2] + xc * wv[j][3];
      float sv = a / (1.f + __expf(-a));
      xb[base + d]  = f2bs(xc);
      xcb[base + d] = f2bs(sv);
      win[j][0] = win[j][1]; win[j][1] = win[j][2]; win[j][2] = xc;
    }
  }
}

// ---------------- K2: headwise projections (+r_bias folded) -> P[h][b][s][e*4+g] ----
__global__ __launch_bounds__(256) void proj_kernel(
    const short* __restrict__ xb, const short* __restrict__ xcb,
    const short* __restrict__ Wbf, const float* __restrict__ rb,
    short* __restrict__ P)
{
  const int hg = blockIdx.y;
  const int h = hg >> 2, g = hg & 3;
  const short* A  = (g < 2) ? xcb : xb;           // gi,gf from conv(x); gz,go from x
  const short* Wb = Wbf + (size_t)hg * (DH_ * DH_);
  const int tid = threadIdx.x, w = tid >> 6, l = tid & 63;
  const int l15 = l & 15, lg = l >> 4;
  const int R0 = blockIdx.x * 256 + w * 64;

  float rbv[12];
#pragma unroll
  for (int nt = 0; nt < 12; ++nt)
    rbv[nt] = rb[(g * NH_ + h) * DH_ + l15 + nt * 16];

  for (int mp = 0; mp < 2; ++mp) {
    const int rb0 = R0 + mp * 32;
    floatx4 acc[2][12];
    for (int u = 0; u < 2; ++u)
      for (int nt = 0; nt < 12; ++nt) acc[u][nt] = (floatx4){0.f, 0.f, 0.f, 0.f};
    const short* Ar = A + (size_t)(rb0 + l15) * D_ + h * DH_ + lg * 8;
    const short* Bp = Wb + l15 * DH_ + lg * 8;
    for (int kk = 0; kk < 6; ++kk) {
      short8 a0 = *(const short8*)(Ar + kk * 32);
      short8 a1 = *(const short8*)(Ar + (size_t)16 * D_ + kk * 32);
      for (int nt = 0; nt < 12; ++nt) {
        short8 bf = *(const short8*)(Bp + nt * 16 * DH_ + kk * 32);
        acc[0][nt] = __builtin_amdgcn_mfma_f32_16x16x32_bf16(a0, bf, acc[0][nt], 0, 0, 0);
        acc[1][nt] = __builtin_amdgcn_mfma_f32_16x16x32_bf16(a1, bf, acc[1][nt], 0, 0, 0);
      }
    }
    for (int u = 0; u < 2; ++u) {
      for (int q = 0; q < 4; ++q) {
        int row = rb0 + u * 16 + lg * 4 + q;
        int s = row & (S_ - 1);
        int bb = row >> 12;
        // packed gate-interleaved layout: column e*4 + g, e = l15 + nt*16
        size_t ob = (((size_t)h * B_ + bb) * S_ + s) * NTOT_ + l15 * 4 + g;
        for (int nt = 0; nt < 12; ++nt)
          P[ob + nt * 64] = f2bs(acc[u][nt][q] + rbv[nt]);
      }
    }
  }
}

// ---------------- K3: sequential sLSTM scan (fma_mix, hybrid reg+LDS R) ----------------
// 768 threads per (h,b) chain. Lane (e,q) = (t0>>2, t0&3): k-slice [48q,48q+48)
// for all 4 gates of element e. Gates 0,1 R in registers (48 dwords, f16-packed);
// gates 2,3 in LDS (144 KB, conflict-free chunk layout). Bias pre-folded into P.
// Inner product via v_fma_mix_f32 (full-rate f32 pipe) -- v_dot2_f32_f16 measured
// quarter-rate across R3-R9 (2304 cy/step floor), fma_mix pairs halve it.
#define RL_BYTES 147456          // 12 chunks * 768 lanes * 16 B
#define CHUNK_B  12288           // 768 lanes * 16 B
__global__ __launch_bounds__(768)
void scan_kernel(short* P_, const float* __restrict__ rk)
{
  const int bid = blockIdx.x;      // 0..31: chain; h = bid>>3, b = bid&7
  const int h = bid >> 3;
  const int t0 = threadIdx.x;      // 0..767
  const int e = t0 >> 2, q = t0 & 3;

  __shared__ __align__(16) char shbuf[RL_BYTES + 2 * DH_ * 2];
  f16* ybuf = (f16*)(shbuf + RL_BYTES);          // y dbuf [2][DH_]

  const float* Rh = rk + (size_t)h * (DH_ * NTOT_);   // [k][g][e]

  // registers: gates 0,1  (48 dwords)
  unsigned Rr[2][24];
#pragma unroll
  for (int j = 0; j < 24; ++j) {
    const int k0 = 48 * q + 2 * j;
#pragma unroll
    for (int g = 0; g < 2; ++g) {
      float v0 = Rh[((size_t)k0 * 4 + g) * DH_ + e];
      float v1 = Rh[((size_t)(k0 + 1) * 4 + g) * DH_ + e];
      Rr[g][j] = packh2(v0, v1);
    }
  }
  // LDS: gates 2,3 -> chunk c (0..5: gate2, 6..11: gate3), 16B per lane per chunk
#pragma unroll
  for (int c = 0; c < 12; ++c) {
    const int gate = 2 + (c >= 6);
    const int m0 = (c % 6) * 4;
    uint4v blk;
#pragma unroll
    for (int j = 0; j < 4; ++j) {
      const int k0 = 48 * q + 2 * (m0 + j);
      blk[j] = packh2(Rh[((size_t)k0 * 4 + gate) * DH_ + e],
                      Rh[((size_t)(k0 + 1) * 4 + gate) * DH_ + e]);
    }
    *(uint4v*)(shbuf + c * CHUNK_B + t0 * 16) = blk;
  }

  if (t0 < DH_) ybuf[t0] = (f16)0.f;

  float c = 0.f, nrm = 0.f, m = 0.f;
  short* Pc = P_ + (size_t)bid * S_ * NTOT_;
  short4v wxc = *(const short4v*)(Pc + e * 4);
  __syncthreads();

  const char* rlz = shbuf + t0 * 16;             // gate2 chunks at +c*CHUNK_B
  const char* rlo = rlz + 6 * CHUNK_B;           // gate3 chunks

#pragma unroll 1
  for (int t = 0; t < S_; ++t) {
    short4v wxn = {};
    if (t + 1 < S_) wxn = *(const short4v*)(Pc + (size_t)(t + 1) * NTOT_ + e * 4);

    const f16* yb = ybuf + (t & 1) * DH_ + q * 48;
    float a0 = 0.f, a1 = 0.f, a2 = 0.f, a3 = 0.f;
#pragma unroll
    for (int i = 0; i < 6; ++i) {
      uint4v Y = *(const uint4v*)(yb + i * 8);
      uint4v Z = *(const uint4v*)(rlz + i * CHUNK_B);
      uint4v O = *(const uint4v*)(rlo + i * CHUNK_B);
#pragma unroll
      for (int u = 0; u < 4; ++u) {
        const int j = i * 4 + u;
        a0 = FMAMIX2(Rr[0][j], Y[u], a0);
        a1 = FMAMIX2(Rr[1][j], Y[u], a1);
        a2 = FMAMIX2(Z[u], Y[u], a2);
        a3 = FMAMIX2(O[u], Y[u], a3);
      }
    }
    // quad butterfly: sum partials over the 4 k-slices (register-only)
    a0 += qperm<0xB1>(a0);  a0 += qperm<0x4E>(a0);
    a1 += qperm<0xB1>(a1);  a1 += qperm<0x4E>(a1);
    a2 += qperm<0xB1>(a2);  a2 += qperm<0x4E>(a2);
    a3 += qperm<0xB1>(a3);  a3 += qperm<0x4E>(a3);

    float ir  = bs2f((unsigned short)wxc[0]) + a0;
    float fr  = bs2f((unsigned short)wxc[1]) + a1;
    float zr  = bs2f((unsigned short)wxc[2]) + a2;
    float orr = bs2f((unsigned short)wxc[3]) + a3;

    float lsf = fminf(fr, 0.f) - __logf(1.f + __expf(-fabsf(fr)));
    float lfm = m + lsf;
    float mnew = fmaxf(ir, lfm);
    float ig = __expf(ir - mnew);
    float fg = __expf(lfm - mnew);
    float e2z = __expf(2.f * zr);
    float tz = 1.f - 2.f * __builtin_amdgcn_rcpf(e2z + 1.f);
    c   = fg * c + ig * tz;
    nrm = fg * nrm + ig;
    m = mnew;
    float sg = __builtin_amdgcn_rcpf(1.f + __expf(-orr));
    float y = sg * c * __builtin_amdgcn_rcpf(nrm);

    f16 yh = (f16)y;
    if (q == 0) {
      ybuf[((t & 1) ^ 1) * DH_ + e] = yh;
      union { f16 hh; short ss; } uv; uv.hh = yh;
      Pc[(size_t)t * NTOT_ + e] = uv.ss;   // y history (row already consumed)
    }
    wxc = wxn;
    __syncthreads();
  }
}

// ---------------- K4: groupnorm over DH per (h,b,s) row ----------------
__global__ __launch_bounds__(256) void gnorm_kernel(
    const short* __restrict__ yws, const float* __restrict__ gnw,
    float* __restrict__ out)
{
  const int row = blockIdx.x * 4 + (threadIdx.x >> 6);   // (h,b,s), 0..131071
  const int l = threadIdx.x & 63;
  const int h = row >> 15;
  const int b = (row >> 12) & 7;
  const int s = row & (S_ - 1);
  const short* yr = yws + (size_t)row * NTOT_;
  float v[3];
  float su = 0.f, sq = 0.f;
#pragma unroll
  for (int j = 0; j < 3; ++j) {
    unsigned short u = (unsigned short)yr[l + j * 64];
    union { unsigned short u; f16 h; } cv; cv.u = u;
    v[j] = (float)cv.h;
    su += v[j]; sq += v[j] * v[j];
  }
  for (int off = 32; off; off >>= 1) {
    su += __shfl_xor(su, off);
    sq += __shfl_xor(sq, off);
  }
  float mean = su * (1.f / DH_);
  float var = sq * (1.f / DH_) - mean * mean;
  float rs = rsqrtf(var + 1e-5f);
  float* orow = out + ((size_t)b * S_ + s) * D_ + h * DH_;
#pragma unroll
  for (int j = 0; j < 3; ++j)
    orow[l + j * 64] = (v[j] - mean) * rs * gnw[h * DH_ + l + j * 64];
}

extern "C" void kernel_launch(void* const* d_in, const int* in_sizes, int n_in,
                              void* d_out, int out_size, void* d_ws, size_t ws_size,
                              hipStream_t stream) {
  const float* x   = (const float*)d_in[0];
  const float* cw  = (const float*)d_in[1];
  const float* cb  = (const float*)d_in[2];
  const float* wf  = (const float*)d_in[3];
  const float* wi  = (const float*)d_in[4];
  const float* wz  = (const float*)d_in[5];
  const float* wo  = (const float*)d_in[6];
  const float* rk  = (const float*)d_in[7];
  const float* rb  = (const float*)d_in[8];
  const float* gnw = (const float*)d_in[9];
  float* out = (float*)d_out;

  // Workspace: P (bf16 Wx, [h][b][s][768]) = 201,326,592 B; Wbf = 1,179,648 B
  short* P   = (short*)d_ws;
  short* Wbf = (short*)((char*)d_ws + (size_t)201326592);
  // Reuse d_out (100,663,296 B) as scratch for bf16 x / conv(x); gnorm overwrites it.
  short* xb  = (short*)d_out;
  short* xcb = (short*)((char*)d_out + (size_t)50331648);

  wconv_kernel<<<dim3(2304), 256, 0, stream>>>(wf, wi, wz, wo, Wbf);
  conv_silu_kernel<<<dim3(512), 256, 0, stream>>>(x, cw, cb, xb, xcb);
  proj_kernel<<<dim3(128, 16), 256, 0, stream>>>(xb, xcb, Wbf, rb, P);
  scan_kernel<<<dim3(32), 768, 0, stream>>>(P, rk);
  gnorm_kernel<<<dim3(32768), 256, 0, stream>>>(P, gnw, out);
}

// Round 11
// 5698.724 us; speedup vs baseline: 1.2072x; 1.2072x over previous
//
#include <hip/hip_runtime.h>
#include <hip/hip_bf16.h>
#include <math.h>

#define B_ 8
#define S_ 4096
#define D_ 768
#define NH_ 4
#define DH_ 192
#define NTOT_ 768   // 4*DH_

typedef __attribute__((ext_vector_type(8))) short short8;
typedef __attribute__((ext_vector_type(4))) float floatx4;
typedef __attribute__((ext_vector_type(4))) short short4v;
typedef __attribute__((ext_vector_type(4))) unsigned int uint4v;
typedef _Float16 f16;

__device__ __forceinline__ short f2bs(float f) {
  union { float f; unsigned u; } v; v.f = f;
  unsigned r = v.u + 0x7FFFu + ((v.u >> 16) & 1u);
  return (short)(r >> 16);
}
__device__ __forceinline__ float bs2f(unsigned short s) {
  union { unsigned u; float f; } v; v.u = ((unsigned)s) << 16;
  return v.f;
}
__device__ __forceinline__ unsigned packh2(float lo, float hi) {
  union { f16 h[2]; unsigned u; } x;
  x.h[0] = (f16)lo; x.h[1] = (f16)hi;
  return x.u;
}

// v_dot2_f32_f16 from VGPR operands (half-rate, 2 MAC/instr; f32 accum)
__device__ __forceinline__ float DOT2(unsigned r, unsigned y, float acc) {
  asm("v_dot2_f32_f16 %0, %1, %2, %0" : "+v"(acc) : "v"(r), "v"(y));
  return acc;
}
// AGPR-resident operand: explicit accvgpr_read then dot2 (both guaranteed-valid)
__device__ __forceinline__ float DOT2A(unsigned ag, unsigned y, float acc) {
  unsigned tmp;
  asm("v_accvgpr_read_b32 %1, %2\n\t"
      "v_dot2_f32_f16 %0, %1, %3, %0"
      : "+v"(acc), "=&v"(tmp) : "a"(ag), "v"(y));
  return acc;
}
// pin a packed value into an AGPR
__device__ __forceinline__ unsigned toAGPR(unsigned v) {
  unsigned a;
  asm("v_accvgpr_write_b32 %0, %1" : "=a"(a) : "v"(v));
  return a;
}

// quad-perm DPP (register-only cross-lane within quad)
template<int CTRL>
__device__ __forceinline__ float qperm(float x) {
  return __int_as_float(__builtin_amdgcn_mov_dpp(__float_as_int(x), CTRL, 0xf, 0xf, true));
}

// ---------------- K0: weights -> bf16, fragment-friendly [hg][o][d] ----------------
__global__ __launch_bounds__(256) void wconv_kernel(
    const float* __restrict__ wf, const float* __restrict__ wi,
    const float* __restrict__ wz, const float* __restrict__ wo,
    short* __restrict__ Wbf)
{
  int idx = blockIdx.x * 256 + threadIdx.x;      // < 16*36864
  int hg = idx / (DH_ * DH_);
  int r  = idx % (DH_ * DH_);
  int h = hg >> 2, g = hg & 3;
  const float* W = (g == 0) ? wf : (g == 1) ? wi : (g == 2) ? wz : wo;
  Wbf[idx] = f2bs(W[(size_t)h * DH_ * DH_ + r]);
}

// ---------------- K1: depthwise causal conv + SiLU; also bf16 copy of x ----------------
__global__ __launch_bounds__(256) void conv_silu_kernel(
    const float* __restrict__ x, const float* __restrict__ cw, const float* __restrict__ cb,
    short* __restrict__ xb, short* __restrict__ xcb)
{
  const int b  = blockIdx.x / (S_ / 64);
  const int s0 = (blockIdx.x % (S_ / 64)) * 64;
  const int tid = threadIdx.x;
  float wv[3][4], bias[3], win[3][3];
  for (int j = 0; j < 3; ++j) {
    int d = tid + j * 256;
    for (int k = 0; k < 4; ++k) wv[j][k] = cw[d * 4 + k];
    bias[j] = cb[d];
    for (int p = 0; p < 3; ++p) {
      int s = s0 - 3 + p;
      win[j][p] = (s >= 0) ? x[((size_t)b * S_ + s) * D_ + d] : 0.f;
    }
  }
  for (int i = 0; i < 64; ++i) {
    size_t base = ((size_t)b * S_ + (s0 + i)) * D_;
    for (int j = 0; j < 3; ++j) {
      int d = tid + j * 256;
      float xc = x[base + d];
      float a = bias[j] + win[j][0] * wv[j][0] + win[j][1] * wv[j][1]
                        + win[j][2] * wv[j][2] + xc * wv[j][3];
      float sv = a / (1.f + __expf(-a));
      xb[base + d]  = f2bs(xc);
      xcb[base + d] = f2bs(sv);
      win[j][0] = win[j][1]; win[j][1] = win[j][2]; win[j][2] = xc;
    }
  }
}

// ---------------- K2: headwise projections (+r_bias folded) -> P[h][b][s][e*4+g] ----
__global__ __launch_bounds__(256) void proj_kernel(
    const short* __restrict__ xb, const short* __restrict__ xcb,
    const short* __restrict__ Wbf, const float* __restrict__ rb,
    short* __restrict__ P)
{
  const int hg = blockIdx.y;
  const int h = hg >> 2, g = hg & 3;
  const short* A  = (g < 2) ? xcb : xb;           // gi,gf from conv(x); gz,go from x
  const short* Wb = Wbf + (size_t)hg * (DH_ * DH_);
  const int tid = threadIdx.x, w = tid >> 6, l = tid & 63;
  const int l15 = l & 15, lg = l >> 4;
  const int R0 = blockIdx.x * 256 + w * 64;

  float rbv[12];
#pragma unroll
  for (int nt = 0; nt < 12; ++nt)
    rbv[nt] = rb[(g * NH_ + h) * DH_ + l15 + nt * 16];

  for (int mp = 0; mp < 2; ++mp) {
    const int rb0 = R0 + mp * 32;
    floatx4 acc[2][12];
    for (int u = 0; u < 2; ++u)
      for (int nt = 0; nt < 12; ++nt) acc[u][nt] = (floatx4){0.f, 0.f, 0.f, 0.f};
    const short* Ar = A + (size_t)(rb0 + l15) * D_ + h * DH_ + lg * 8;
    const short* Bp = Wb + l15 * DH_ + lg * 8;
    for (int kk = 0; kk < 6; ++kk) {
      short8 a0 = *(const short8*)(Ar + kk * 32);
      short8 a1 = *(const short8*)(Ar + (size_t)16 * D_ + kk * 32);
      for (int nt = 0; nt < 12; ++nt) {
        short8 bf = *(const short8*)(Bp + nt * 16 * DH_ + kk * 32);
        acc[0][nt] = __builtin_amdgcn_mfma_f32_16x16x32_bf16(a0, bf, acc[0][nt], 0, 0, 0);
        acc[1][nt] = __builtin_amdgcn_mfma_f32_16x16x32_bf16(a1, bf, acc[1][nt], 0, 0, 0);
      }
    }
    for (int u = 0; u < 2; ++u) {
      for (int q = 0; q < 4; ++q) {
        int row = rb0 + u * 16 + lg * 4 + q;
        int s = row & (S_ - 1);
        int bb = row >> 12;
        // packed gate-interleaved layout: column e*4 + g, e = l15 + nt*16
        size_t ob = (((size_t)h * B_ + bb) * S_ + s) * NTOT_ + l15 * 4 + g;
        for (int nt = 0; nt < 12; ++nt)
          P[ob + nt * 64] = f2bs(acc[u][nt][q] + rbv[nt]);
      }
    }
  }
}

// ---------------- K3: sequential sLSTM scan (reg + AGPR R storage) ----------------
// 768 threads per (h,b) chain. Lane (e,q) = (t0>>2, t0&3): k-slice [48q,48q+48)
// for all 4 gates of element e. Gates 0,1 R in VGPRs (48 dwords); gates 2,3 R
// PINNED IN AGPRS via inline-asm "a" constraints (48 dwords) -- removes the
// 144KB/step LDS RL stream (R9's binding ~1700cy) for +48 full-rate
// accvgpr_reads (+288cy). Bias pre-folded into P by proj_kernel.
__global__ __launch_bounds__(768)
void scan_kernel(short* P_, const float* __restrict__ rk)
{
  const int bid = blockIdx.x;      // 0..31: chain; h = bid>>3, b = bid&7
  const int h = bid >> 3;
  const int t0 = threadIdx.x;      // 0..767
  const int e = t0 >> 2, q = t0 & 3;

  __shared__ __align__(16) f16 ybuf[2][DH_];

  const float* Rh = rk + (size_t)h * (DH_ * NTOT_);   // [k][g][e]

  // gates 0,1 -> VGPRs; gates 2,3 -> AGPRs
  unsigned Rr[2][24];
  unsigned zA[24], oA[24];
#pragma unroll
  for (int j = 0; j < 24; ++j) {
    const int k0 = 48 * q + 2 * j;
    Rr[0][j] = packh2(Rh[((size_t)k0 * 4 + 0) * DH_ + e],
                      Rh[((size_t)(k0 + 1) * 4 + 0) * DH_ + e]);
    Rr[1][j] = packh2(Rh[((size_t)k0 * 4 + 1) * DH_ + e],
                      Rh[((size_t)(k0 + 1) * 4 + 1) * DH_ + e]);
    zA[j] = toAGPR(packh2(Rh[((size_t)k0 * 4 + 2) * DH_ + e],
                          Rh[((size_t)(k0 + 1) * 4 + 2) * DH_ + e]));
    oA[j] = toAGPR(packh2(Rh[((size_t)k0 * 4 + 3) * DH_ + e],
                          Rh[((size_t)(k0 + 1) * 4 + 3) * DH_ + e]));
  }

  if (t0 < DH_) ybuf[0][t0] = (f16)0.f;

  float c = 0.f, nrm = 0.f, m = 0.f;
  short* Pc = P_ + (size_t)bid * S_ * NTOT_;
  short4v wxc = *(const short4v*)(Pc + e * 4);
  __syncthreads();

#pragma unroll 1
  for (int t = 0; t < S_; ++t) {
    short4v wxn = {};
    if (t + 1 < S_) wxn = *(const short4v*)(Pc + (size_t)(t + 1) * NTOT_ + e * 4);

    const f16* yb = &ybuf[t & 1][q * 48];
    float a0 = 0.f, a1 = 0.f, a2 = 0.f, a3 = 0.f;
#pragma unroll
    for (int i = 0; i < 6; ++i) {
      uint4v Y = *(const uint4v*)(yb + i * 8);
#pragma unroll
      for (int u = 0; u < 4; ++u) {
        const int j = i * 4 + u;
        a0 = DOT2(Rr[0][j], Y[u], a0);
        a1 = DOT2(Rr[1][j], Y[u], a1);
        a2 = DOT2A(zA[j], Y[u], a2);
        a3 = DOT2A(oA[j], Y[u], a3);
      }
    }
    // quad butterfly: sum partials over the 4 k-slices (register-only)
    a0 += qperm<0xB1>(a0);  a0 += qperm<0x4E>(a0);
    a1 += qperm<0xB1>(a1);  a1 += qperm<0x4E>(a1);
    a2 += qperm<0xB1>(a2);  a2 += qperm<0x4E>(a2);
    a3 += qperm<0xB1>(a3);  a3 += qperm<0x4E>(a3);

    float ir  = bs2f((unsigned short)wxc[0]) + a0;
    float fr  = bs2f((unsigned short)wxc[1]) + a1;
    float zr  = bs2f((unsigned short)wxc[2]) + a2;
    float orr = bs2f((unsigned short)wxc[3]) + a3;

    float lsf = fminf(fr, 0.f) - __logf(1.f + __expf(-fabsf(fr)));
    float lfm = m + lsf;
    float mnew = fmaxf(ir, lfm);
    float ig = __expf(ir - mnew);
    float fg = __expf(lfm - mnew);
    float e2z = __expf(2.f * zr);
    float tz = 1.f - 2.f * __builtin_amdgcn_rcpf(e2z + 1.f);
    c   = fg * c + ig * tz;
    nrm = fg * nrm + ig;
    m = mnew;
    float sg = __builtin_amdgcn_rcpf(1.f + __expf(-orr));
    float y = sg * c * __builtin_amdgcn_rcpf(nrm);

    f16 yh = (f16)y;
    if (q == 0) {
      ybuf[(t & 1) ^ 1][e] = yh;
      union { f16 hh; short ss; } uv; uv.hh = yh;
      Pc[(size_t)t * NTOT_ + e] = uv.ss;   // y history (row already consumed)
    }
    wxc = wxn;
    __syncthreads();
  }
}

// ---------------- K4: groupnorm over DH per (h,b,s) row ----------------
__global__ __launch_bounds__(256) void gnorm_kernel(
    const short* __restrict__ yws, const float* __restrict__ gnw,
    float* __restrict__ out)
{
  const int row = blockIdx.x * 4 + (threadIdx.x >> 6);   // (h,b,s), 0..131071
  const int l = threadIdx.x & 63;
  const int h = row >> 15;
  const int b = (row >> 12) & 7;
  const int s = row & (S_ - 1);
  const short* yr = yws + (size_t)row * NTOT_;
  float v[3];
  float su = 0.f, sq = 0.f;
#pragma unroll
  for (int j = 0; j < 3; ++j) {
    unsigned short u = (unsigned short)yr[l + j * 64];
    union { unsigned short u; f16 h; } cv; cv.u = u;
    v[j] = (float)cv.h;
    su += v[j]; sq += v[j] * v[j];
  }
  for (int off = 32; off; off >>= 1) {
    su += __shfl_xor(su, off);
    sq += __shfl_xor(sq, off);
  }
  float mean = su * (1.f / DH_);
  float var = sq * (1.f / DH_) - mean * mean;
  float rs = rsqrtf(var + 1e-5f);
  float* orow = out + ((size_t)b * S_ + s) * D_ + h * DH_;
#pragma unroll
  for (int j = 0; j < 3; ++j)
    orow[l + j * 64] = (v[j] - mean) * rs * gnw[h * DH_ + l + j * 64];
}

extern "C" void kernel_launch(void* const* d_in, const int* in_sizes, int n_in,
                              void* d_out, int out_size, void* d_ws, size_t ws_size,
                              hipStream_t stream) {
  const float* x   = (const float*)d_in[0];
  const float* cw  = (const float*)d_in[1];
  const float* cb  = (const float*)d_in[2];
  const float* wf  = (const float*)d_in[3];
  const float* wi  = (const float*)d_in[4];
  const float* wz  = (const float*)d_in[5];
  const float* wo  = (const float*)d_in[6];
  const float* rk  = (const float*)d_in[7];
  const float* rb  = (const float*)d_in[8];
  const float* gnw = (const float*)d_in[9];
  float* out = (float*)d_out;

  // Workspace: P (bf16 Wx, [h][b][s][768]) = 201,326,592 B; Wbf = 1,179,648 B
  short* P   = (short*)d_ws;
  short* Wbf = (short*)((char*)d_ws + (size_t)201326592);
  // Reuse d_out (100,663,296 B) as scratch for bf16 x / conv(x); gnorm overwrites it.
  short* xb  = (short*)d_out;
  short* xcb = (short*)((char*)d_out + (size_t)50331648);

  wconv_kernel<<<dim3(2304), 256, 0, stream>>>(wf, wi, wz, wo, Wbf);
  conv_silu_kernel<<<dim3(512), 256, 0, stream>>>(x, cw, cb, xb, xcb);
  proj_kernel<<<dim3(128, 16), 256, 0, stream>>>(xb, xcb, Wbf, rb, P);
  scan_kernel<<<dim3(32), 768, 0, stream>>>(P, rk);
  gnorm_kernel<<<dim3(32768), 256, 0, stream>>>(P, gnw, out);
}

// Round 12
// 5687.498 us; speedup vs baseline: 1.2096x; 1.0020x over previous
//
#include <hip/hip_runtime.h>
#include <hip/hip_bf16.h>
#include <math.h>

#define B_ 8
#define S_ 4096
#define D_ 768
#define NH_ 4
#define DH_ 192
#define NTOT_ 768   // 4*DH_

typedef __attribute__((ext_vector_type(8))) short short8;
typedef __attribute__((ext_vector_type(4))) float floatx4;
typedef __attribute__((ext_vector_type(4))) short short4v;
typedef __attribute__((ext_vector_type(4))) unsigned int uint4v;
typedef _Float16 f16;

__device__ __forceinline__ short f2bs(float f) {
  union { float f; unsigned u; } v; v.f = f;
  unsigned r = v.u + 0x7FFFu + ((v.u >> 16) & 1u);
  return (short)(r >> 16);
}
__device__ __forceinline__ float bs2f(unsigned short s) {
  union { unsigned u; float f; } v; v.u = ((unsigned)s) << 16;
  return v.f;
}
__device__ __forceinline__ unsigned packh2(float lo, float hi) {
  union { f16 h[2]; unsigned u; } x;
  x.h[0] = (f16)lo; x.h[1] = (f16)hi;
  return x.u;
}

// v_dot2_f32_f16 (quarter-rate, but only 24/lane/step now; f32 accum)
__device__ __forceinline__ float DOT2(unsigned r, unsigned y, float acc) {
  asm("v_dot2_f32_f16 %0, %1, %2, %0" : "+v"(acc) : "v"(r), "v"(y));
  return acc;
}

// quad-perm DPP (register-only cross-lane within quad)
template<int CTRL>
__device__ __forceinline__ float qperm(float x) {
  return __int_as_float(__builtin_amdgcn_mov_dpp(__float_as_int(x), CTRL, 0xf, 0xf, true));
}

// ---------------- K0: weights -> bf16, fragment-friendly [hg][o][d] ----------------
__global__ __launch_bounds__(256) void wconv_kernel(
    const float* __restrict__ wf, const float* __restrict__ wi,
    const float* __restrict__ wz, const float* __restrict__ wo,
    short* __restrict__ Wbf)
{
  int idx = blockIdx.x * 256 + threadIdx.x;      // < 16*36864
  int hg = idx / (DH_ * DH_);
  int r  = idx % (DH_ * DH_);
  int h = hg >> 2, g = hg & 3;
  const float* W = (g == 0) ? wf : (g == 1) ? wi : (g == 2) ? wz : wo;
  Wbf[idx] = f2bs(W[(size_t)h * DH_ * DH_ + r]);
}

// ---------------- K1: depthwise causal conv + SiLU; also bf16 copy of x ----------------
__global__ __launch_bounds__(256) void conv_silu_kernel(
    const float* __restrict__ x, const float* __restrict__ cw, const float* __restrict__ cb,
    short* __restrict__ xb, short* __restrict__ xcb)
{
  const int b  = blockIdx.x / (S_ / 64);
  const int s0 = (blockIdx.x % (S_ / 64)) * 64;
  const int tid = threadIdx.x;
  float wv[3][4], bias[3], win[3][3];
  for (int j = 0; j < 3; ++j) {
    int d = tid + j * 256;
    for (int k = 0; k < 4; ++k) wv[j][k] = cw[d * 4 + k];
    bias[j] = cb[d];
    for (int p = 0; p < 3; ++p) {
      int s = s0 - 3 + p;
      win[j][p] = (s >= 0) ? x[((size_t)b * S_ + s) * D_ + d] : 0.f;
    }
  }
  for (int i = 0; i < 64; ++i) {
    size_t base = ((size_t)b * S_ + (s0 + i)) * D_;
    for (int j = 0; j < 3; ++j) {
      int d = tid + j * 256;
      float xc = x[base + d];
      float a = bias[j] + win[j][0] * wv[j][0] + win[j][1] * wv[j][1]
                        + win[j][2] * wv[j][2] + xc * wv[j][3];
      float sv = a / (1.f + __expf(-a));
      xb[base + d]  = f2bs(xc);
      xcb[base + d] = f2bs(sv);
      win[j][0] = win[j][1]; win[j][1] = win[j][2]; win[j][2] = xc;
    }
  }
}

// ---------------- K2: headwise projections (+r_bias folded) -> P[h][b][s][e*4+g] ----
__global__ __launch_bounds__(256) void proj_kernel(
    const short* __restrict__ xb, const short* __restrict__ xcb,
    const short* __restrict__ Wbf, const float* __restrict__ rb,
    short* __restrict__ P)
{
  const int hg = blockIdx.y;
  const int h = hg >> 2, g = hg & 3;
  const short* A  = (g < 2) ? xcb : xb;           // gi,gf from conv(x); gz,go from x
  const short* Wb = Wbf + (size_t)hg * (DH_ * DH_);
  const int tid = threadIdx.x, w = tid >> 6, l = tid & 63;
  const int l15 = l & 15, lg = l >> 4;
  const int R0 = blockIdx.x * 256 + w * 64;

  float rbv[12];
#pragma unroll
  for (int nt = 0; nt < 12; ++nt)
    rbv[nt] = rb[(g * NH_ + h) * DH_ + l15 + nt * 16];

  for (int mp = 0; mp < 2; ++mp) {
    const int rb0 = R0 + mp * 32;
    floatx4 acc[2][12];
    for (int u = 0; u < 2; ++u)
      for (int nt = 0; nt < 12; ++nt) acc[u][nt] = (floatx4){0.f, 0.f, 0.f, 0.f};
    const short* Ar = A + (size_t)(rb0 + l15) * D_ + h * DH_ + lg * 8;
    const short* Bp = Wb + l15 * DH_ + lg * 8;
    for (int kk = 0; kk < 6; ++kk) {
      short8 a0 = *(const short8*)(Ar + kk * 32);
      short8 a1 = *(const short8*)(Ar + (size_t)16 * D_ + kk * 32);
      for (int nt = 0; nt < 12; ++nt) {
        short8 bf = *(const short8*)(Bp + nt * 16 * DH_ + kk * 32);
        acc[0][nt] = __builtin_amdgcn_mfma_f32_16x16x32_bf16(a0, bf, acc[0][nt], 0, 0, 0);
        acc[1][nt] = __builtin_amdgcn_mfma_f32_16x16x32_bf16(a1, bf, acc[1][nt], 0, 0, 0);
      }
    }
    for (int u = 0; u < 2; ++u) {
      for (int q = 0; q < 4; ++q) {
        int row = rb0 + u * 16 + lg * 4 + q;
        int s = row & (S_ - 1);
        int bb = row >> 12;
        // packed gate-interleaved layout: column e*4 + g, e = l15 + nt*16
        size_t ob = (((size_t)h * B_ + bb) * S_ + s) * NTOT_ + l15 * 4 + g;
        for (int nt = 0; nt < 12; ++nt)
          P[ob + nt * 64] = f2bs(acc[u][nt][q] + rbv[nt]);
      }
    }
  }
}

// ---------------- K3: sLSTM scan: MFMA (gates f,z,o) + dot2 (gate i) hybrid ----------
// 768 threads (12 waves) per (h,b) chain.
// MFMA side: wave w owns col window e in [w*16, w*16+16) for gates f,z,o
//   (3 tiles x 6 k-steps = 18 MFMA/wave/step). A = row-broadcast y (bf16 LDS).
//   B-frags (72 dwords) + acc (12) only touched by MFMA -> AGPR placement is free.
// dot2 side: lane (e,q)=(t0>>2,t0&3) computes gate i for element e over k-slice
//   [48q,48q+48): 24 dot2 + quad butterfly (Ri = 24 VGPRs, fits the 84 budget).
// Phase2: gate math per lane e (4x quad-redundant); f,z,o raws via small LDS.
__global__ __launch_bounds__(768)
void scan_kernel(short* P_, const float* __restrict__ rk)
{
  const int bid = blockIdx.x;      // 0..31: chain; h = bid>>3, b = bid&7
  const int h = bid >> 3;
  const int t0 = threadIdx.x;      // 0..767
  const int e = t0 >> 2, q = t0 & 3;           // dot/gate mapping
  const int w = t0 >> 6, l = t0 & 63;          // wave mapping
  const int l15 = l & 15, lg = l >> 4;

  __shared__ __align__(16) f16 y_f16[DH_];
  __shared__ __align__(16) unsigned short y_bf[DH_];
  __shared__ __align__(16) float raw_lds[3][DH_];   // f,z,o raws

  const float* Rh = rk + (size_t)h * (DH_ * NTOT_);   // [k][g][e]: Rh[k*768+g*192+e]

  // dot2 R for gate i (g=0): k-slice 48q.., packed f16 pairs (24 VGPRs)
  unsigned Ri[24];
#pragma unroll
  for (int j = 0; j < 24; ++j) {
    const int k0 = 48 * q + 2 * j;
    Ri[j] = packh2(Rh[(size_t)k0 * NTOT_ + e], Rh[(size_t)(k0 + 1) * NTOT_ + e]);
  }

  // MFMA B-fragments for gates 1..3, col = w*16 + l15 (bf16, memory-order k)
  short8 Bf[3][6];
#pragma unroll
  for (int gg = 0; gg < 3; ++gg) {
#pragma unroll
    for (int kk = 0; kk < 6; ++kk) {
      short8 v;
#pragma unroll
      for (int j = 0; j < 8; ++j) {
        const int k = kk * 32 + lg * 8 + j;
        v[j] = f2bs(Rh[(size_t)k * NTOT_ + (gg + 1) * DH_ + w * 16 + l15]);
      }
      Bf[gg][kk] = v;
    }
  }

  if (t0 < DH_) { y_f16[t0] = (f16)0.f; y_bf[t0] = 0; }

  float c = 0.f, nrm = 0.f, m = 0.f;
  short* Pc = P_ + (size_t)bid * S_ * NTOT_;
  short4v wxc = *(const short4v*)(Pc + e * 4);
  __syncthreads();

#pragma unroll 1
  for (int t = 0; t < S_; ++t) {
    short4v wxn = {};
    if (t + 1 < S_) wxn = *(const short4v*)(Pc + (size_t)(t + 1) * NTOT_ + e * 4);

    // ---- phase 1: MFMA (f,z,o) + dot2 (i) off the same y ----
    floatx4 acc0 = (floatx4){0.f,0.f,0.f,0.f};
    floatx4 acc1 = (floatx4){0.f,0.f,0.f,0.f};
    floatx4 acc2 = (floatx4){0.f,0.f,0.f,0.f};
    float a0 = 0.f;
#pragma unroll
    for (int kk = 0; kk < 6; ++kk) {
      short8 A = *(const short8*)((const short*)y_bf + kk * 32 + lg * 8);
      acc0 = __builtin_amdgcn_mfma_f32_16x16x32_bf16(A, Bf[0][kk], acc0, 0, 0, 0);
      acc1 = __builtin_amdgcn_mfma_f32_16x16x32_bf16(A, Bf[1][kk], acc1, 0, 0, 0);
      acc2 = __builtin_amdgcn_mfma_f32_16x16x32_bf16(A, Bf[2][kk], acc2, 0, 0, 0);
      uint4v Y = *(const uint4v*)((const f16*)y_f16 + q * 48 + kk * 8);
      a0 = DOT2(Ri[kk * 4 + 0], Y[0], a0);
      a0 = DOT2(Ri[kk * 4 + 1], Y[1], a0);
      a0 = DOT2(Ri[kk * 4 + 2], Y[2], a0);
      a0 = DOT2(Ri[kk * 4 + 3], Y[3], a0);
    }
    // quad butterfly for gate i (4 k-slices)
    a0 += qperm<0xB1>(a0);  a0 += qperm<0x4E>(a0);
    // publish f,z,o raws (rows identical due to broadcast A; take reg 0, lanes 0-15)
    if (l < 16) {
      raw_lds[0][w * 16 + l] = acc0[0];
      raw_lds[1][w * 16 + l] = acc1[0];
      raw_lds[2][w * 16 + l] = acc2[0];
    }
    __syncthreads();

    // ---- phase 2: gate math per element e (quad-redundant) ----
    float ir  = bs2f((unsigned short)wxc[0]) + a0;
    float fr  = bs2f((unsigned short)wxc[1]) + raw_lds[0][e];
    float zr  = bs2f((unsigned short)wxc[2]) + raw_lds[1][e];
    float orr = bs2f((unsigned short)wxc[3]) + raw_lds[2][e];

    float lsf = fminf(fr, 0.f) - __logf(1.f + __expf(-fabsf(fr)));
    float lfm = m + lsf;
    float mnew = fmaxf(ir, lfm);
    float ig = __expf(ir - mnew);
    float fg = __expf(lfm - mnew);
    float e2z = __expf(2.f * zr);
    float tz = 1.f - 2.f * __builtin_amdgcn_rcpf(e2z + 1.f);
    c   = fg * c + ig * tz;
    nrm = fg * nrm + ig;
    m = mnew;
    float sg = __builtin_amdgcn_rcpf(1.f + __expf(-orr));
    float y = sg * c * __builtin_amdgcn_rcpf(nrm);

    if (q == 0) {
      f16 yh = (f16)y;
      y_f16[e] = yh;
      y_bf[e] = (unsigned short)f2bs(y);
      union { f16 hh; short ss; } uv; uv.hh = yh;
      Pc[(size_t)t * NTOT_ + e] = uv.ss;   // y history (row already consumed)
    }
    wxc = wxn;
    __syncthreads();
  }
}

// ---------------- K4: groupnorm over DH per (h,b,s) row ----------------
__global__ __launch_bounds__(256) void gnorm_kernel(
    const short* __restrict__ yws, const float* __restrict__ gnw,
    float* __restrict__ out)
{
  const int row = blockIdx.x * 4 + (threadIdx.x >> 6);   // (h,b,s), 0..131071
  const int l = threadIdx.x & 63;
  const int h = row >> 15;
  const int b = (row >> 12) & 7;
  const int s = row & (S_ - 1);
  const short* yr = yws + (size_t)row * NTOT_;
  float v[3];
  float su = 0.f, sq = 0.f;
#pragma unroll
  for (int j = 0; j < 3; ++j) {
    unsigned short u = (unsigned short)yr[l + j * 64];
    union { unsigned short u; f16 h; } cv; cv.u = u;
    v[j] = (float)cv.h;
    su += v[j]; sq += v[j] * v[j];
  }
  for (int off = 32; off; off >>= 1) {
    su += __shfl_xor(su, off);
    sq += __shfl_xor(sq, off);
  }
  float mean = su * (1.f / DH_);
  float var = sq * (1.f / DH_) - mean * mean;
  float rs = rsqrtf(var + 1e-5f);
  float* orow = out + ((size_t)b * S_ + s) * D_ + h * DH_;
#pragma unroll
  for (int j = 0; j < 3; ++j)
    orow[l + j * 64] = (v[j] - mean) * rs * gnw[h * DH_ + l + j * 64];
}

extern "C" void kernel_launch(void* const* d_in, const int* in_sizes, int n_in,
                              void* d_out, int out_size, void* d_ws, size_t ws_size,
                              hipStream_t stream) {
  const float* x   = (const float*)d_in[0];
  const float* cw  = (const float*)d_in[1];
  const float* cb  = (const float*)d_in[2];
  const float* wf  = (const float*)d_in[3];
  const float* wi  = (const float*)d_in[4];
  const float* wz  = (const float*)d_in[5];
  const float* wo  = (const float*)d_in[6];
  const float* rk  = (const float*)d_in[7];
  const float* rb  = (const float*)d_in[8];
  const float* gnw = (const float*)d_in[9];
  float* out = (float*)d_out;

  // Workspace: P (bf16 Wx, [h][b][s][768]) = 201,326,592 B; Wbf = 1,179,648 B
  short* P   = (short*)d_ws;
  short* Wbf = (short*)((char*)d_ws + (size_t)201326592);
  // Reuse d_out (100,663,296 B) as scratch for bf16 x / conv(x); gnorm overwrites it.
  short* xb  = (short*)d_out;
  short* xcb = (short*)((char*)d_out + (size_t)50331648);

  wconv_kernel<<<dim3(2304), 256, 0, stream>>>(wf, wi, wz, wo, Wbf);
  conv_silu_kernel<<<dim3(512), 256, 0, stream>>>(x, cw, cb, xb, xcb);
  proj_kernel<<<dim3(128, 16), 256, 0, stream>>>(xb, xcb, Wbf, rb, P);
  scan_kernel<<<dim3(32), 768, 0, stream>>>(P, rk);
  gnorm_kernel<<<dim3(32768), 256, 0, stream>>>(P, gnw, out);
}

// Round 14
// 5425.974 us; speedup vs baseline: 1.2679x; 1.0482x over previous
//
#include <hip/hip_runtime.h>
#include <hip/hip_bf16.h>
#include <math.h>

#define B_ 8
#define S_ 4096
#define D_ 768
#define NH_ 4
#define DH_ 192
#define NTOT_ 768   // 4*DH_

typedef __attribute__((ext_vector_type(8))) short short8;
typedef __attribute__((ext_vector_type(4))) float floatx4;
typedef __attribute__((ext_vector_type(4))) short short4v;
typedef _Float16 f16;
typedef __attribute__((ext_vector_type(8))) _Float16 h8;

__device__ __forceinline__ short f2bs(float f) {
  union { float f; unsigned u; } v; v.f = f;
  unsigned r = v.u + 0x7FFFu + ((v.u >> 16) & 1u);
  return (short)(r >> 16);
}
__device__ __forceinline__ float bs2f(unsigned short s) {
  union { unsigned u; float f; } v; v.u = ((unsigned)s) << 16;
  return v.f;
}

// ---------------- K0: weights -> bf16, fragment-friendly [hg][o][d] ----------------
__global__ __launch_bounds__(256) void wconv_kernel(
    const float* __restrict__ wf, const float* __restrict__ wi,
    const float* __restrict__ wz, const float* __restrict__ wo,
    short* __restrict__ Wbf)
{
  int idx = blockIdx.x * 256 + threadIdx.x;      // < 16*36864
  int hg = idx / (DH_ * DH_);
  int r  = idx % (DH_ * DH_);
  int h = hg >> 2, g = hg & 3;
  const float* W = (g == 0) ? wf : (g == 1) ? wi : (g == 2) ? wz : wo;
  Wbf[idx] = f2bs(W[(size_t)h * DH_ * DH_ + r]);
}

// ---------------- K1: depthwise causal conv + SiLU; also bf16 copy of x ----------------
__global__ __launch_bounds__(256) void conv_silu_kernel(
    const float* __restrict__ x, const float* __restrict__ cw, const float* __restrict__ cb,
    short* __restrict__ xb, short* __restrict__ xcb)
{
  const int b  = blockIdx.x / (S_ / 64);
  const int s0 = (blockIdx.x % (S_ / 64)) * 64;
  const int tid = threadIdx.x;
  float wv[3][4], bias[3], win[3][3];
  for (int j = 0; j < 3; ++j) {
    int d = tid + j * 256;
    for (int k = 0; k < 4; ++k) wv[j][k] = cw[d * 4 + k];
    bias[j] = cb[d];
    for (int p = 0; p < 3; ++p) {
      int s = s0 - 3 + p;
      win[j][p] = (s >= 0) ? x[((size_t)b * S_ + s) * D_ + d] : 0.f;
    }
  }
  for (int i = 0; i < 64; ++i) {
    size_t base = ((size_t)b * S_ + (s0 + i)) * D_;
    for (int j = 0; j < 3; ++j) {
      int d = tid + j * 256;
      float xc = x[base + d];
      float a = bias[j] + win[j][0] * wv[j][0] + win[j][1] * wv[j][1]
                        + win[j][2] * wv[j][2] + xc * wv[j][3];
      float sv = a / (1.f + __expf(-a));
      xb[base + d]  = f2bs(xc);
      xcb[base + d] = f2bs(sv);
      win[j][0] = win[j][1]; win[j][1] = win[j][2]; win[j][2] = xc;
    }
  }
}

// ---------------- K2: headwise projections (+r_bias folded) -> P[h][b][s][e*4+g] ----
__global__ __launch_bounds__(256) void proj_kernel(
    const short* __restrict__ xb, const short* __restrict__ xcb,
    const short* __restrict__ Wbf, const float* __restrict__ rb,
    short* __restrict__ P)
{
  const int hg = blockIdx.y;
  const int h = hg >> 2, g = hg & 3;
  const short* A  = (g < 2) ? xcb : xb;           // gi,gf from conv(x); gz,go from x
  const short* Wb = Wbf + (size_t)hg * (DH_ * DH_);
  const int tid = threadIdx.x, w = tid >> 6, l = tid & 63;
  const int l15 = l & 15, lg = l >> 4;
  const int R0 = blockIdx.x * 256 + w * 64;

  float rbv[12];
#pragma unroll
  for (int nt = 0; nt < 12; ++nt)
    rbv[nt] = rb[(g * NH_ + h) * DH_ + l15 + nt * 16];

  for (int mp = 0; mp < 2; ++mp) {
    const int rb0 = R0 + mp * 32;
    floatx4 acc[2][12];
    for (int u = 0; u < 2; ++u)
      for (int nt = 0; nt < 12; ++nt) acc[u][nt] = (floatx4){0.f, 0.f, 0.f, 0.f};
    const short* Ar = A + (size_t)(rb0 + l15) * D_ + h * DH_ + lg * 8;
    const short* Bp = Wb + l15 * DH_ + lg * 8;
    for (int kk = 0; kk < 6; ++kk) {
      short8 a0 = *(const short8*)(Ar + kk * 32);
      short8 a1 = *(const short8*)(Ar + (size_t)16 * D_ + kk * 32);
      for (int nt = 0; nt < 12; ++nt) {
        short8 bf = *(const short8*)(Bp + nt * 16 * DH_ + kk * 32);
        acc[0][nt] = __builtin_amdgcn_mfma_f32_16x16x32_bf16(a0, bf, acc[0][nt], 0, 0, 0);
        acc[1][nt] = __builtin_amdgcn_mfma_f32_16x16x32_bf16(a1, bf, acc[1][nt], 0, 0, 0);
      }
    }
    for (int u = 0; u < 2; ++u) {
      for (int q = 0; q < 4; ++q) {
        int row = rb0 + u * 16 + lg * 4 + q;
        int s = row & (S_ - 1);
        int bb = row >> 12;
        // packed gate-interleaved layout: column e*4 + g, e = l15 + nt*16
        size_t ob = (((size_t)h * B_ + bb) * S_ + s) * NTOT_ + l15 * 4 + g;
        for (int nt = 0; nt < 12; ++nt)
          P[ob + nt * 64] = f2bs(acc[u][nt][q] + rbv[nt]);
      }
    }
  }
}

// ---------------- K3: sLSTM scan, 8 chains batched in MFMA M dimension (f16) ----------
// ONE WG (768 thr, 12 waves) per head h; the 8 chains (b=0..7) ride in MFMA
// A-rows 0-7 (rows 8-15 zero). 288 MFMA/CU/step amortized over 8 chains.
// BUILTIN f16 MFMA (hazard handling + f16 precision, the class every passing
// round used; R13's inline-asm bf16 variant failed absmax). Wave w owns
// n-tiles {g*12+w} = 4 gates of e-window [16w,16w+16) -> raw exchange is
// intra-wave LDS, no barrier. Gate math: exactly 2 (chain,e) pairs/thread.
// One barrier/step.
__global__ __launch_bounds__(768)
void scan_kernel(short* P_, const float* __restrict__ rk)
{
  const int h  = blockIdx.x;       // 0..3
  const int t0 = threadIdx.x;
  const int w  = t0 >> 6, l = t0 & 63;
  const int l15 = l & 15, lg = l >> 4;

  __shared__ __align__(16) f16 y_lds[2][16][200];        // f16, rows 8-15 = 0
  __shared__ __align__(16) float raw_lds[12][8][16][4];  // [wave][chain][e4][gate]

  const float* Rh = rk + (size_t)h * (DH_ * NTOT_);   // [k][g*192+e]

  // B-fragments (f16): wave w, gate g -> n-window g*192 + 16w .. +16
  h8 Bf[4][6];
#pragma unroll
  for (int g = 0; g < 4; ++g) {
#pragma unroll
    for (int kk = 0; kk < 6; ++kk) {
      h8 v;
#pragma unroll
      for (int j = 0; j < 8; ++j) {
        const int k = kk * 32 + lg * 8 + j;
        v[j] = (f16)Rh[(size_t)k * NTOT_ + g * DH_ + w * 16 + l15];
      }
      Bf[g][kk] = v;
    }
  }

  for (int idx = t0; idx < 2 * 16 * 200; idx += 768)
    ((f16*)y_lds)[idx] = (f16)0.f;

  const int e  = w * 16 + l15;         // this thread's element
  const int c0 = lg, c1 = lg + 4;      // its two chains
  short* Pb0 = P_ + ((size_t)(h * B_ + c0) * S_) * NTOT_;
  short* Pb1 = P_ + ((size_t)(h * B_ + c1) * S_) * NTOT_;

  float cc0 = 0.f, nn0 = 0.f, mm0 = 0.f;
  float cc1 = 0.f, nn1 = 0.f, mm1 = 0.f;
  short4v wxc0 = *(const short4v*)(Pb0 + e * 4);
  short4v wxc1 = *(const short4v*)(Pb1 + e * 4);
  __syncthreads();

#pragma unroll 1
  for (int t = 0; t < S_; ++t) {
    short4v wxn0 = {}, wxn1 = {};
    if (t + 1 < S_) {
      wxn0 = *(const short4v*)(Pb0 + (size_t)(t + 1) * NTOT_ + e * 4);
      wxn1 = *(const short4v*)(Pb1 + (size_t)(t + 1) * NTOT_ + e * 4);
    }
    const int cur = t & 1, nxt = cur ^ 1;

    // ---- matvec: 24 builtin f16 MFMA/wave; A rows = chains ----
    floatx4 a0 = (floatx4){0.f,0.f,0.f,0.f};
    floatx4 a1 = (floatx4){0.f,0.f,0.f,0.f};
    floatx4 a2 = (floatx4){0.f,0.f,0.f,0.f};
    floatx4 a3 = (floatx4){0.f,0.f,0.f,0.f};
#pragma unroll
    for (int kk = 0; kk < 6; ++kk) {
      h8 A = *(const h8*)&y_lds[cur][l15][kk * 32 + lg * 8];
      a0 = __builtin_amdgcn_mfma_f32_16x16x32_f16(A, Bf[0][kk], a0, 0, 0, 0);
      a1 = __builtin_amdgcn_mfma_f32_16x16x32_f16(A, Bf[1][kk], a1, 0, 0, 0);
      a2 = __builtin_amdgcn_mfma_f32_16x16x32_f16(A, Bf[2][kk], a2, 0, 0, 0);
      a3 = __builtin_amdgcn_mfma_f32_16x16x32_f16(A, Bf[3][kk], a3, 0, 0, 0);
    }
    // ---- intra-wave raw exchange: D row (l>>4)*4+j = chain, col l15 = e4 ----
    if (l < 32) {
#pragma unroll
      for (int j = 0; j < 4; ++j) {
        floatx4 v = (floatx4){a0[j], a1[j], a2[j], a3[j]};
        *(floatx4*)&raw_lds[w][lg * 4 + j][l15][0] = v;
      }
    }
    floatx4 r0 = *(const floatx4*)&raw_lds[w][c0][l15][0];
    floatx4 r1 = *(const floatx4*)&raw_lds[w][c1][l15][0];

    // ---- gate math: chain c0 ----
    f16 yh0, yh1;
    {
      float ir  = bs2f((unsigned short)wxc0[0]) + r0[0];
      float fr  = bs2f((unsigned short)wxc0[1]) + r0[1];
      float zr  = bs2f((unsigned short)wxc0[2]) + r0[2];
      float orr = bs2f((unsigned short)wxc0[3]) + r0[3];
      float lsf = fminf(fr, 0.f) - __logf(1.f + __expf(-fabsf(fr)));
      float lfm = mm0 + lsf;
      float mnew = fmaxf(ir, lfm);
      float ig = __expf(ir - mnew);
      float fg = __expf(lfm - mnew);
      float e2z = __expf(2.f * zr);
      float tz = 1.f - 2.f * __builtin_amdgcn_rcpf(e2z + 1.f);
      cc0 = fg * cc0 + ig * tz;
      nn0 = fg * nn0 + ig;
      mm0 = mnew;
      float sg = __builtin_amdgcn_rcpf(1.f + __expf(-orr));
      yh0 = (f16)(sg * cc0 * __builtin_amdgcn_rcpf(nn0));
    }
    // ---- chain c1 ----
    {
      float ir  = bs2f((unsigned short)wxc1[0]) + r1[0];
      float fr  = bs2f((unsigned short)wxc1[1]) + r1[1];
      float zr  = bs2f((unsigned short)wxc1[2]) + r1[2];
      float orr = bs2f((unsigned short)wxc1[3]) + r1[3];
      float lsf = fminf(fr, 0.f) - __logf(1.f + __expf(-fabsf(fr)));
      float lfm = mm1 + lsf;
      float mnew = fmaxf(ir, lfm);
      float ig = __expf(ir - mnew);
      float fg = __expf(lfm - mnew);
      float e2z = __expf(2.f * zr);
      float tz = 1.f - 2.f * __builtin_amdgcn_rcpf(e2z + 1.f);
      cc1 = fg * cc1 + ig * tz;
      nn1 = fg * nn1 + ig;
      mm1 = mnew;
      float sg = __builtin_amdgcn_rcpf(1.f + __expf(-orr));
      yh1 = (f16)(sg * cc1 * __builtin_amdgcn_rcpf(nn1));
    }

    // y broadcast (f16 A for next step) + f16 history for gnorm (same bits)
    y_lds[nxt][c0][e] = yh0;
    y_lds[nxt][c1][e] = yh1;
    {
      union { f16 hh; short ss; } u0, u1;
      u0.hh = yh0; u1.hh = yh1;
      Pb0[(size_t)t * NTOT_ + e] = u0.ss;
      Pb1[(size_t)t * NTOT_ + e] = u1.ss;
    }
    wxc0 = wxn0; wxc1 = wxn1;
    __syncthreads();
  }
}

// ---------------- K4: groupnorm over DH per (h,b,s) row ----------------
__global__ __launch_bounds__(256) void gnorm_kernel(
    const short* __restrict__ yws, const float* __restrict__ gnw,
    float* __restrict__ out)
{
  const int row = blockIdx.x * 4 + (threadIdx.x >> 6);   // (h,b,s), 0..131071
  const int l = threadIdx.x & 63;
  const int h = row >> 15;
  const int b = (row >> 12) & 7;
  const int s = row & (S_ - 1);
  const short* yr = yws + (size_t)row * NTOT_;
  float v[3];
  float su = 0.f, sq = 0.f;
#pragma unroll
  for (int j = 0; j < 3; ++j) {
    unsigned short u = (unsigned short)yr[l + j * 64];
    union { unsigned short u; f16 h; } cv; cv.u = u;
    v[j] = (float)cv.h;
    su += v[j]; sq += v[j] * v[j];
  }
  for (int off = 32; off; off >>= 1) {
    su += __shfl_xor(su, off);
    sq += __shfl_xor(sq, off);
  }
  float mean = su * (1.f / DH_);
  float var = sq * (1.f / DH_) - mean * mean;
  float rs = rsqrtf(var + 1e-5f);
  float* orow = out + ((size_t)b * S_ + s) * D_ + h * DH_;
#pragma unroll
  for (int j = 0; j < 3; ++j)
    orow[l + j * 64] = (v[j] - mean) * rs * gnw[h * DH_ + l + j * 64];
}

extern "C" void kernel_launch(void* const* d_in, const int* in_sizes, int n_in,
                              void* d_out, int out_size, void* d_ws, size_t ws_size,
                              hipStream_t stream) {
  const float* x   = (const float*)d_in[0];
  const float* cw  = (const float*)d_in[1];
  const float* cb  = (const float*)d_in[2];
  const float* wf  = (const float*)d_in[3];
  const float* wi  = (const float*)d_in[4];
  const float* wz  = (const float*)d_in[5];
  const float* wo  = (const float*)d_in[6];
  const float* rk  = (const float*)d_in[7];
  const float* rb  = (const float*)d_in[8];
  const float* gnw = (const float*)d_in[9];
  float* out = (float*)d_out;

  // Workspace: P (bf16 Wx, [h][b][s][768]) = 201,326,592 B; Wbf = 1,179,648 B
  short* P   = (short*)d_ws;
  short* Wbf = (short*)((char*)d_ws + (size_t)201326592);
  // Reuse d_out (100,663,296 B) as scratch for bf16 x / conv(x); gnorm overwrites it.
  short* xb  = (short*)d_out;
  short* xcb = (short*)((char*)d_out + (size_t)50331648);

  wconv_kernel<<<dim3(2304), 256, 0, stream>>>(wf, wi, wz, wo, Wbf);
  conv_silu_kernel<<<dim3(512), 256, 0, stream>>>(x, cw, cb, xb, xcb);
  proj_kernel<<<dim3(128, 16), 256, 0, stream>>>(xb, xcb, Wbf, rb, P);
  scan_kernel<<<dim3(4), 768, 0, stream>>>(P, rk);
  gnorm_kernel<<<dim3(32768), 256, 0, stream>>>(P, gnw, out);
}